// Round 1
// 416.855 us; speedup vs baseline: 1.0026x; 1.0026x over previous
//
#include <hip/hip_runtime.h>
#include <hip/hip_bf16.h>

// Problem constants
#define B_  2
#define S_  2048
#define HID_ 2048
#define H_  16
#define HKV_ 4
#define D_  128

typedef __bf16 bf16_t;
typedef bf16_t bf16x8 __attribute__((ext_vector_type(8)));
typedef float f32x4 __attribute__((ext_vector_type(4)));

typedef __attribute__((address_space(3))) unsigned int lds_u32_t;
typedef const __attribute__((address_space(1))) unsigned int glob_u32_t;

// async global->LDS, 16 B per lane; LDS dest = wave-uniform base + lane*16
__device__ __forceinline__ void gl2lds16(const bf16_t* g, bf16_t* l) {
    __builtin_amdgcn_global_load_lds((glob_u32_t*)g, (lds_u32_t*)l, 16, 0, 0);
}

__device__ __forceinline__ unsigned packbf2(float a, float b) {
    union { bf16_t h[2]; unsigned u; } p;
    p.h[0] = (bf16_t)a;
    p.h[1] = (bf16_t)b;
    return p.u;
}

// ---------------------------------------------------------------------------
// Runtime dtype detection: flag=1 if inputs are bf16, 0 if fp32.
// ---------------------------------------------------------------------------
__global__ void detect_dtype(const unsigned* __restrict__ x, int* __restrict__ flag) {
    int lane = threadIdx.x;
    int c = 0;
#pragma unroll
    for (int i = 0; i < 16; ++i) {
        unsigned w = x[lane * 16 + i];
        unsigned e = (w >> 7) & 0xFF;
        c += (e >= 117 && e <= 137) ? 1 : 0;
    }
#pragma unroll
    for (int m = 1; m < 64; m <<= 1) c += __shfl_xor(c, m, 64);
    if (lane == 0) *flag = (c >= 512) ? 1 : 0;
}

// ---------------------------------------------------------------------------
// Conversion pass: src (fp32 or bf16 per flag) -> bf16 dst. 8 elems/thread.
// ---------------------------------------------------------------------------
struct Cseg { const void* src; bf16_t* dst; int n8; };

__global__ __launch_bounds__(256) void convert_bf16(Cseg s0, Cseg s1, Cseg s2, Cseg s3,
                                                    const int* __restrict__ flagp) {
    Cseg s = (blockIdx.y == 0) ? s0 : (blockIdx.y == 1) ? s1 : (blockIdx.y == 2) ? s2 : s3;
    const int i = blockIdx.x * 256 + threadIdx.x;
    if (i >= s.n8) return;
    if (*flagp) {
        ((uint4*)s.dst)[i] = ((const uint4*)s.src)[i];
    } else {
        const float4* p = (const float4*)s.src + (size_t)i * 2;
        float4 u = p[0], v = p[1];
        bf16x8 r;
        r[0] = (bf16_t)u.x; r[1] = (bf16_t)u.y; r[2] = (bf16_t)u.z; r[3] = (bf16_t)u.w;
        r[4] = (bf16_t)v.x; r[5] = (bf16_t)v.y; r[6] = (bf16_t)v.z; r[7] = (bf16_t)v.w;
        *(bf16x8*)(s.dst + (size_t)i * 8) = r;
    }
}

// ---------------------------------------------------------------------------
// m97-structure GEMM: C[m,n] = sum_k A[m,k]*W[n,k], A/W bf16 row-major.
// 128x128 tile, BK=32, LDS staging via global_load_lds width=16.
// ---------------------------------------------------------------------------
__global__ __launch_bounds__(256) void gemm_lds(const bf16_t* __restrict__ A,
                                                const bf16_t* __restrict__ W,
                                                void* __restrict__ C,
                                                int M, int N, int K,
                                                const int* __restrict__ flagp, int osel) {
    __shared__ bf16_t As[128 * 32];
    __shared__ bf16_t Bs[128 * 32];

    const int tid = threadIdx.x;
    const int w = tid >> 6;
    const int lane = tid & 63;
    const int r = lane & 15;
    const int quad = lane >> 4;
    const int m0 = blockIdx.y * 128;
    const int n0 = blockIdx.x * 128;
    const bool of32 = osel && (*flagp == 0);

    const int mh = (w & 1) * 64;
    const int nh = (w >> 1) * 64;

    const int c0 = w * 2;
    const int srow = lane >> 2;
    const int scol = (lane & 3) * 8;
    const bf16_t* Ag0 = A + (size_t)(m0 + c0 * 16 + srow) * K + scol;
    const bf16_t* Ag1 = A + (size_t)(m0 + c0 * 16 + 16 + srow) * K + scol;
    const bf16_t* Wg0 = W + (size_t)(n0 + c0 * 16 + srow) * K + scol;
    const bf16_t* Wg1 = W + (size_t)(n0 + c0 * 16 + 16 + srow) * K + scol;
    bf16_t* Al0 = As + c0 * 512;
    bf16_t* Al1 = As + (c0 + 1) * 512;
    bf16_t* Bl0 = Bs + c0 * 512;
    bf16_t* Bl1 = Bs + (c0 + 1) * 512;

    f32x4 acc[4][4] = {};

    for (int k0 = 0; k0 < K; k0 += 32) {
        __syncthreads();
        gl2lds16(Ag0 + k0, Al0);
        gl2lds16(Ag1 + k0, Al1);
        gl2lds16(Wg0 + k0, Bl0);
        gl2lds16(Wg1 + k0, Bl1);
        __syncthreads();

        bf16x8 a[4], b[4];
#pragma unroll
        for (int mi = 0; mi < 4; ++mi)
            a[mi] = *(const bf16x8*)&As[(mh + mi * 16 + r) * 32 + quad * 8];
#pragma unroll
        for (int ni = 0; ni < 4; ++ni)
            b[ni] = *(const bf16x8*)&Bs[(nh + ni * 16 + r) * 32 + quad * 8];
#pragma unroll
        for (int mi = 0; mi < 4; ++mi)
#pragma unroll
            for (int ni = 0; ni < 4; ++ni)
                acc[mi][ni] = __builtin_amdgcn_mfma_f32_16x16x32_bf16(a[mi], b[ni], acc[mi][ni], 0, 0, 0);
    }

#pragma unroll
    for (int mi = 0; mi < 4; ++mi) {
#pragma unroll
        for (int ni = 0; ni < 4; ++ni) {
#pragma unroll
            for (int g = 0; g < 4; ++g) {
                const int row = m0 + mh + mi * 16 + quad * 4 + g;
                const int col = n0 + nh + ni * 16 + r;
                if (of32) ((float*)C)[(size_t)row * N + col] = acc[mi][ni][g];
                else ((__hip_bfloat16*)C)[(size_t)row * N + col] = __float2bfloat16(acc[mi][ni][g]);
            }
        }
    }
}

// ---------------------------------------------------------------------------
// Fallback direct-from-global GEMM (proven path).
// ---------------------------------------------------------------------------
template <bool F32>
__device__ __forceinline__ bf16x8 load8(const void* base, size_t off) {
    bf16x8 r;
    if constexpr (F32) {
        const float4* p = (const float4*)((const float*)base + off);
        float4 u = p[0], v = p[1];
        r[0] = (bf16_t)u.x; r[1] = (bf16_t)u.y; r[2] = (bf16_t)u.z; r[3] = (bf16_t)u.w;
        r[4] = (bf16_t)v.x; r[5] = (bf16_t)v.y; r[6] = (bf16_t)v.z; r[7] = (bf16_t)v.w;
    } else {
        r = *(const bf16x8*)((const bf16_t*)base + off);
    }
    return r;
}

template <bool AF32, bool WF32, bool OF32>
__device__ __forceinline__ void gemm_body(const void* __restrict__ A, const void* __restrict__ W,
                                          void* __restrict__ C, int M, int N, int K) {
    const int wave = threadIdx.x >> 6;
    const int lane = threadIdx.x & 63;
    const int r = lane & 15;
    const int quad = lane >> 4;
    const int m0 = blockIdx.y * 64 + wave * 16;
    const int n0 = blockIdx.x * 64;

    f32x4 acc[4] = {};
    const size_t aoff = (size_t)(m0 + r) * K + quad * 8;
    const size_t woff = (size_t)(n0 + r) * K + quad * 8;

    for (int k0 = 0; k0 < K; k0 += 32) {
        bf16x8 a = load8<AF32>(A, aoff + k0);
#pragma unroll
        for (int ns = 0; ns < 4; ++ns) {
            bf16x8 b = load8<WF32>(W, woff + (size_t)(ns * 16) * K + k0);
            acc[ns] = __builtin_amdgcn_mfma_f32_16x16x32_bf16(a, b, acc[ns], 0, 0, 0);
        }
    }

#pragma unroll
    for (int ns = 0; ns < 4; ++ns) {
#pragma unroll
        for (int reg = 0; reg < 4; ++reg) {
            int m = m0 + quad * 4 + reg;
            int n = n0 + ns * 16 + r;
            if constexpr (OF32) ((float*)C)[(size_t)m * N + n] = acc[ns][reg];
            else ((__hip_bfloat16*)C)[(size_t)m * N + n] = __float2bfloat16(acc[ns][reg]);
        }
    }
}

__global__ __launch_bounds__(256) void gemm_bt(const void* __restrict__ A, const void* __restrict__ W,
                                               void* __restrict__ C, int M, int N, int K,
                                               const int* __restrict__ flagp, int mode) {
    const int bf = *flagp;
    if (bf) {
        gemm_body<false, false, false>(A, W, C, M, N, K);
    } else if (mode == 0) {
        gemm_body<true, true, false>(A, W, C, M, N, K);
    } else {
        gemm_body<false, true, true>(A, W, C, M, N, K);
    }
}

// ---------------------------------------------------------------------------
// In-place RoPE + RMSNorm on bf16 rows. Row (bs,h) at base + bs*ld + h*D.
// ---------------------------------------------------------------------------
__global__ __launch_bounds__(256) void rope_rms(__hip_bfloat16* __restrict__ qk,
                                                const void* __restrict__ cosp,
                                                const void* __restrict__ sinp,
                                                int NH, int ld, const int* __restrict__ flagp) {
    const int bf = *flagp;
    const int wave = threadIdx.x >> 6;
    const int lane = threadIdx.x & 63;
    const int row = blockIdx.x * 4 + wave;   // row = bs*NH + h
    const int h = row % NH;
    const int bs = row / NH;
    const int s = bs % S_;

    __hip_bfloat16* p = qk + (size_t)bs * ld + h * D_;
    float x1 = __bfloat162float(p[lane]);
    float x2 = __bfloat162float(p[lane + 64]);
    float c, sn, eps;
    if (bf) {
        c   = __bfloat162float(((const __hip_bfloat16*)cosp)[s * 64 + lane]);
        sn  = __bfloat162float(((const __hip_bfloat16*)sinp)[s * 64 + lane]);
        eps = 0.0078125f;
    } else {
        c   = ((const float*)cosp)[s * 64 + lane];
        sn  = ((const float*)sinp)[s * 64 + lane];
        eps = 1.1920929e-07f;
    }
    float y1 = x1 * c + x2 * sn;
    float y2 = x2 * c - x1 * sn;
    float ss = y1 * y1 + y2 * y2;
#pragma unroll
    for (int m = 1; m < 64; m <<= 1) ss += __shfl_xor(ss, m, 64);
    float rinv = rsqrtf(ss * (1.0f / 128.0f) + eps);
    p[lane]      = __float2bfloat16(y1 * rinv);
    p[lane + 64] = __float2bfloat16(y2 * rinv);
}

// ---------------------------------------------------------------------------
// V pair-pack transpose: V[s][d] (strided in qkv) -> Vp[g][d][s/32][kp] u32
// where u32 = (V[32t+kp][d], V[32t+16+kp][d]).  This is exactly the fragment
// pair order the Pb path produces (kp = quad*4 + word), so PV B-frags become
// single contiguous 16 B loads.  1M threads, one u32 each; writes coalesced.
// ---------------------------------------------------------------------------
__global__ __launch_bounds__(256) void v_pack(const __hip_bfloat16* __restrict__ V,
                                              unsigned* __restrict__ Vp, int ldv) {
    const int idx = blockIdx.x * 256 + threadIdx.x;
    const int kp = idx & 15;
    const int t  = (idx >> 4) & 63;
    const int d  = (idx >> 10) & 127;
    const int gy = idx >> 17;                 // b*HKV + kvh
    const int kvh = gy & 3;
    const int b = gy >> 2;
    const unsigned short* p = (const unsigned short*)V
        + (size_t)(b * S_ + 32 * t + kp) * ldv + kvh * D_ + d;
    unsigned lo = p[0];
    unsigned hi = p[(size_t)16 * ldv];
    Vp[idx] = lo | (hi << 16);
}

// ---------------------------------------------------------------------------
// Flash attention v4: barrier-free K-loop, direct-from-L2 K/V reads.
//
// Why: v3 was latency-bound (MfmaUtil 9%, occupancy 12.7% == ~1 block/CU
// average from causal imbalance; 4 barrier-locked waves, ~6000 cyc/iter).
// K/V per (b,kvh) group is 1 MB -> L2-resident, so LDS staging (and both
// per-iteration barriers) are pure overhead.
//
// Structure: grid = 256 blocks (1/CU, forced by 81 KB LDS), 8 waves.
//   block id: gy = id&7 (group -> XCD-pinned via round-robin), px = id>>3.
//   Each block serially does q-tiles {px, 63-px} (constant 65 key-tiles).
//   wave w: head hh=w&3, half=w>>2. Half 0 does keys [0,nkt/2), half 1 does
//   [nkt/2,nkt) incl. diagonal -> per SIMD one A(32u)+one B(33u) wave:
//   exact static balance, 2 independent waves/SIMD the whole runtime.
//   Per-tile merge of (m,l,O) partials via LDS + 2 barriers (vs 130 in v3).
//
// K-frags: 16 B loads straight from global K (post-RoPE, in qkv).
// V-frags: 16 B loads from pre-packed Vp (the Vt/Pb xor swizzle cancels:
//   frag word w of lane quad needs pair kp = quad*4+w -> linear layout).
// Softmax / Pb pair-pack path identical to v3 (wave-private, lgkmcnt only).
// ---------------------------------------------------------------------------
__global__ __launch_bounds__(512, 2) void attn_flash4(const __hip_bfloat16* __restrict__ Q,
                                                      const __hip_bfloat16* __restrict__ K,
                                                      const unsigned* __restrict__ Vp,
                                                      __hip_bfloat16* __restrict__ O,
                                                      int ldq, int ldkv, int ldo) {
    __shared__ unsigned Pb[8][2][16][16];   // 16 KB, wave-private P pair-pack
    __shared__ float Of[4][32][128];        // 64 KB, half-1 partial O
    __shared__ float Ml[4][2][2][16];       // 1 KB,  half-1 partial m,l

    const int tid = threadIdx.x;
    const int w = tid >> 6;
    const int lane = tid & 63;
    const int r = lane & 15;
    const int quad = lane >> 4;

    const int id = blockIdx.x;
    const int gy = id & 7;                  // group -> XCD pin
    const int px = id >> 3;                 // 0..31 tile-pair index
    const int kvh = gy & 3;
    const int b = gy >> 2;
    const int hh = w & 3;
    const int half = w >> 2;
    const int h = kvh * 4 + hh;

    const bf16_t* Kg = (const bf16_t*)K + (size_t)b * S_ * ldkv + kvh * D_;
    const unsigned* Vg = Vp + (size_t)gy * (D_ * 64 * 16);

    bf16x8 ones;
#pragma unroll
    for (int j = 0; j < 8; ++j) ones[j] = (bf16_t)1.0f;

    const float SC2 = 0.08838834764831845f * 1.4426950408889634f;  // D^-0.5 * log2(e)

    for (int rep = 0; rep < 2; ++rep) {
        const int qt = rep ? (63 - px) : px;
        const int q0 = qt * 32;
        const int nkt = qt + 1;
        const int ktb = half ? (nkt >> 1) : 0;
        const int kte = half ? nkt : (nkt >> 1);

        // Q fragments for this tile
        bf16x8 qf[2][4];
#pragma unroll
        for (int t = 0; t < 2; ++t) {
            const bf16_t* qp = (const bf16_t*)Q + (size_t)(b * S_ + q0 + t * 16 + r) * ldq + h * D_ + quad * 8;
#pragma unroll
            for (int c = 0; c < 4; ++c) qf[t][c] = *(const bf16x8*)(qp + c * 32);
        }

        f32x4 oacc[2][8] = {};
        f32x4 lacc[2] = {};
        float m_i[2][4];
#pragma unroll
        for (int t = 0; t < 2; ++t)
#pragma unroll
            for (int g = 0; g < 4; ++g) m_i[t][g] = -3e38f;

        for (int kt = ktb; kt < kte; ++kt) {
            const int k0 = kt * 32;
            const bf16_t* kp0 = Kg + (size_t)(k0 + r) * ldkv + quad * 8;

            // ---- QK^T straight from L2 ----
            f32x4 s0[2] = {}, s1[2] = {};
            __builtin_amdgcn_s_setprio(1);
#pragma unroll
            for (int c = 0; c < 4; ++c) {
                bf16x8 kb0 = *(const bf16x8*)(kp0 + c * 32);
                bf16x8 kb1 = *(const bf16x8*)(kp0 + (size_t)16 * ldkv + c * 32);
#pragma unroll
                for (int t = 0; t < 2; ++t) {
                    s0[t] = __builtin_amdgcn_mfma_f32_16x16x32_bf16(qf[t][c], kb0, s0[t], 0, 0, 0);
                    s1[t] = __builtin_amdgcn_mfma_f32_16x16x32_bf16(qf[t][c], kb1, s1[t], 0, 0, 0);
                }
            }
            __builtin_amdgcn_s_setprio(0);

            const bool bnd = (kt == qt);
#pragma unroll
            for (int t = 0; t < 2; ++t) {
                float mt[4];
#pragma unroll
                for (int g = 0; g < 4; ++g) {
                    s0[t][g] *= SC2;
                    s1[t][g] *= SC2;
                    if (bnd) {
                        const int qrow = q0 + t * 16 + quad * 4 + g;
                        if (k0 + r > qrow)      s0[t][g] = -1e38f;
                        if (k0 + 16 + r > qrow) s1[t][g] = -1e38f;
                    }
                    mt[g] = fmaxf(s0[t][g], s1[t][g]);
                }
#pragma unroll
                for (int msk = 1; msk < 16; msk <<= 1) {
#pragma unroll
                    for (int g = 0; g < 4; ++g) mt[g] = fmaxf(mt[g], __shfl_xor(mt[g], msk, 64));
                }
                // ballot-gated rescale
                bool upd = false;
#pragma unroll
                for (int g = 0; g < 4; ++g) upd |= (mt[g] > m_i[t][g]);
                if (__ballot(upd)) {
#pragma unroll
                    for (int g = 0; g < 4; ++g) {
                        const float mn = fmaxf(m_i[t][g], mt[g]);
                        const float al = exp2f(m_i[t][g] - mn);
                        m_i[t][g] = mn;
                        lacc[t][g] *= al;
#pragma unroll
                        for (int ns = 0; ns < 8; ++ns) oacc[t][ns][g] *= al;
                    }
                }
                // p = 2^(s-m); pair-packed store (key r | key 16+r)
#pragma unroll
                for (int g = 0; g < 4; ++g) {
                    const float p0 = exp2f(s0[t][g] - m_i[t][g]);
                    const float p1 = exp2f(s1[t][g] - m_i[t][g]);
                    const int row = quad * 4 + g;
                    Pb[w][t][row][(((r >> 2) ^ quad) & 3) * 4 + (r & 3)] = packbf2(p0, p1);
                }
            }

            const int pgrp = ((quad ^ (r >> 2)) & 3) * 4;
            bf16x8 pf0 = *(const bf16x8*)&Pb[w][0][r][pgrp];
            bf16x8 pf1 = *(const bf16x8*)&Pb[w][1][r][pgrp];

            // row-sum l via ones-column MFMA (perm-invariant)
            lacc[0] = __builtin_amdgcn_mfma_f32_16x16x32_bf16(pf0, ones, lacc[0], 0, 0, 0);
            lacc[1] = __builtin_amdgcn_mfma_f32_16x16x32_bf16(pf1, ones, lacc[1], 0, 0, 0);

            // ---- PV: V-frags straight from packed global (L2) ----
            const unsigned* vp = Vg + (size_t)r * (64 * 16) + kt * 16 + quad * 4;
            __builtin_amdgcn_s_setprio(1);
#pragma unroll
            for (int ns = 0; ns < 8; ++ns) {
                bf16x8 vf = *(const bf16x8*)(vp + (size_t)ns * 16 * 64 * 16);
                oacc[0][ns] = __builtin_amdgcn_mfma_f32_16x16x32_bf16(pf0, vf, oacc[0][ns], 0, 0, 0);
                oacc[1][ns] = __builtin_amdgcn_mfma_f32_16x16x32_bf16(pf1, vf, oacc[1][ns], 0, 0, 0);
            }
            __builtin_amdgcn_s_setprio(0);
        }

        // ---- per-tile merge of the two key-halves ----
        if (half) {
#pragma unroll
            for (int t = 0; t < 2; ++t) {
                if (r == 0) {
#pragma unroll
                    for (int g = 0; g < 4; ++g) {
                        Ml[hh][t][0][quad * 4 + g] = m_i[t][g];
                        Ml[hh][t][1][quad * 4 + g] = lacc[t][g];
                    }
                }
#pragma unroll
                for (int ns = 0; ns < 8; ++ns)
#pragma unroll
                    for (int g = 0; g < 4; ++g)
                        Of[hh][t * 16 + quad * 4 + g][ns * 16 + r] = oacc[t][ns][g];
            }
        }
        __syncthreads();
        if (!half) {
#pragma unroll
            for (int t = 0; t < 2; ++t) {
#pragma unroll
                for (int g = 0; g < 4; ++g) {
                    const int r16 = quad * 4 + g;
                    const float mB = Ml[hh][t][0][r16];
                    const float lB = Ml[hh][t][1][r16];
                    const float mA = m_i[t][g];
                    const float mx = fmaxf(mA, mB);
                    const float aA = exp2f(mA - mx);
                    const float aB = exp2f(mB - mx);
                    const float inv = 1.0f / (lacc[t][g] * aA + lB * aB);
                    const int qrow = q0 + t * 16 + r16;
                    __hip_bfloat16* op = O + (size_t)(b * S_ + qrow) * ldo + h * D_;
#pragma unroll
                    for (int ns = 0; ns < 8; ++ns) {
                        const float v = (oacc[t][ns][g] * aA + Of[hh][t * 16 + r16][ns * 16 + r] * aB) * inv;
                        op[ns * 16 + r] = __float2bfloat16(v);
                    }
                }
            }
        }
        __syncthreads();
    }
}

// ---------------------------------------------------------------------------
// Flash attention v3 (kept for the fallback path).
// ---------------------------------------------------------------------------
#define KT_ 32
#define LDK 136

__global__ __launch_bounds__(256, 2) void attn_flash3(const __hip_bfloat16* __restrict__ Q,
                                                      const __hip_bfloat16* __restrict__ K,
                                                      const __hip_bfloat16* __restrict__ V,
                                                      __hip_bfloat16* __restrict__ O,
                                                      int ldq, int ldkv, int ldo) {
    __shared__ unsigned short Ks[KT_][LDK];        // 8704 B
    __shared__ unsigned int Vt[D_ * 16];           // 8192 B (pair-packed)
    __shared__ unsigned int Pb[4][2][16][16];      // 8192 B (pair-packed)

    const int tid = threadIdx.x;
    const int w = tid >> 6;
    const int lane = tid & 63;
    const int r = lane & 15;
    const int quad = lane >> 4;

    const int gy = blockIdx.y;                     // b*HKV + kvh
    const int kvh = gy % HKV_;
    const int b = gy / HKV_;
    const int qt = b ? blockIdx.x : (gridDim.x - 1 - blockIdx.x);
    const int q0 = qt * 32;
    const int h = kvh * 4 + w;

    bf16x8 qf[2][4];
#pragma unroll
    for (int t = 0; t < 2; ++t) {
        const bf16_t* qp = (const bf16_t*)Q + (size_t)(b * S_ + q0 + t * 16 + r) * ldq + h * D_ + quad * 8;
#pragma unroll
        for (int c = 0; c < 4; ++c) qf[t][c] = *(const bf16x8*)(qp + c * 32);
    }

    f32x4 oacc[2][8] = {};
    f32x4 lacc[2] = {};
    float m_i[2][4];
#pragma unroll
    for (int t = 0; t < 2; ++t)
#pragma unroll
        for (int g = 0; g < 4; ++g) m_i[t][g] = -3e38f;

    const bf16_t* Kg = (const bf16_t*)K + (size_t)b * S_ * ldkv + kvh * D_;
    const bf16_t* Vg = (const bf16_t*)V + (size_t)b * S_ * ldkv + kvh * D_;

    bf16x8 ones;
#pragma unroll
    for (int j = 0; j < 8; ++j) ones[j] = (bf16_t)1.0f;

    const float SC2 = 0.08838834764831845f * 1.4426950408889634f;

    const int skey = tid >> 4;
    const int sdc = tid & 15;
    union U4 { uint4 u; unsigned short s[8]; };
    U4 rk0, rk1, rv0, rv1;
    {
        const size_t o0 = (size_t)skey * ldkv + sdc * 8;
        const size_t o1 = o0 + (size_t)16 * ldkv;
        rk0.u = *(const uint4*)(Kg + o0);
        rk1.u = *(const uint4*)(Kg + o1);
        rv0.u = *(const uint4*)(Vg + o0);
        rv1.u = *(const uint4*)(Vg + o1);
    }

    for (int kt = 0; kt <= qt; ++kt) {
        const int k0 = kt * KT_;
        __syncthreads();
        *(uint4*)&Ks[skey][sdc * 8] = rk0.u;
        *(uint4*)&Ks[skey + 16][sdc * 8] = rk1.u;
#pragma unroll
        for (int j = 0; j < 8; ++j) {
            const int d = sdc * 8 + j;
            const int f = ((j >> 1) & 3) ^ (sdc & 3);
            const int grp = (skey >> 2) ^ f;
            Vt[d * 16 + grp * 4 + (skey & 3)] = (unsigned)rv0.s[j] | ((unsigned)rv1.s[j] << 16);
        }
        __syncthreads();
        if (kt < qt) {
            const size_t o0 = (size_t)(k0 + KT_ + skey) * ldkv + sdc * 8;
            const size_t o1 = o0 + (size_t)16 * ldkv;
            rk0.u = *(const uint4*)(Kg + o0);
            rk1.u = *(const uint4*)(Kg + o1);
            rv0.u = *(const uint4*)(Vg + o0);
            rv1.u = *(const uint4*)(Vg + o1);
        }

        f32x4 s0[2] = {}, s1[2] = {};
#pragma unroll
        for (int c = 0; c < 4; ++c) {
            bf16x8 kb0 = *(const bf16x8*)&Ks[r][c * 32 + quad * 8];
            bf16x8 kb1 = *(const bf16x8*)&Ks[16 + r][c * 32 + quad * 8];
#pragma unroll
            for (int t = 0; t < 2; ++t) {
                s0[t] = __builtin_amdgcn_mfma_f32_16x16x32_bf16(qf[t][c], kb0, s0[t], 0, 0, 0);
                s1[t] = __builtin_amdgcn_mfma_f32_16x16x32_bf16(qf[t][c], kb1, s1[t], 0, 0, 0);
            }
        }

        const bool bnd = (kt == qt);
#pragma unroll
        for (int t = 0; t < 2; ++t) {
            float mt[4];
#pragma unroll
            for (int g = 0; g < 4; ++g) {
                s0[t][g] *= SC2;
                s1[t][g] *= SC2;
                if (bnd) {
                    const int qrow = q0 + t * 16 + quad * 4 + g;
                    if (k0 + r > qrow)      s0[t][g] = -1e38f;
                    if (k0 + 16 + r > qrow) s1[t][g] = -1e38f;
                }
                mt[g] = fmaxf(s0[t][g], s1[t][g]);
            }
#pragma unroll
            for (int msk = 1; msk < 16; msk <<= 1) {
#pragma unroll
                for (int g = 0; g < 4; ++g) mt[g] = fmaxf(mt[g], __shfl_xor(mt[g], msk, 64));
            }
            bool upd = false;
#pragma unroll
            for (int g = 0; g < 4; ++g) upd |= (mt[g] > m_i[t][g]);
            if (__ballot(upd)) {
#pragma unroll
                for (int g = 0; g < 4; ++g) {
                    const float mn = fmaxf(m_i[t][g], mt[g]);
                    const float al = exp2f(m_i[t][g] - mn);
                    m_i[t][g] = mn;
                    lacc[t][g] *= al;
#pragma unroll
                    for (int ns = 0; ns < 8; ++ns) oacc[t][ns][g] *= al;
                }
            }
#pragma unroll
            for (int g = 0; g < 4; ++g) {
                const float p0 = exp2f(s0[t][g] - m_i[t][g]);
                const float p1 = exp2f(s1[t][g] - m_i[t][g]);
                const int row = quad * 4 + g;
                Pb[w][t][row][(((r >> 2) ^ quad) & 3) * 4 + (r & 3)] = packbf2(p0, p1);
            }
        }

        const int pgrp = ((quad ^ (r >> 2)) & 3) * 4;
        bf16x8 pf0 = *(const bf16x8*)&Pb[w][0][r][pgrp];
        bf16x8 pf1 = *(const bf16x8*)&Pb[w][1][r][pgrp];

        lacc[0] = __builtin_amdgcn_mfma_f32_16x16x32_bf16(pf0, ones, lacc[0], 0, 0, 0);
        lacc[1] = __builtin_amdgcn_mfma_f32_16x16x32_bf16(pf1, ones, lacc[1], 0, 0, 0);

#pragma unroll
        for (int ns = 0; ns < 8; ++ns) {
            const int d = ns * 16 + r;
            const int f = ((r >> 1) & 3) ^ ((2 * ns + (r >> 3)) & 3);
            bf16x8 vf = *(const bf16x8*)&Vt[d * 16 + ((quad ^ f) & 3) * 4];
            oacc[0][ns] = __builtin_amdgcn_mfma_f32_16x16x32_bf16(pf0, vf, oacc[0][ns], 0, 0, 0);
            oacc[1][ns] = __builtin_amdgcn_mfma_f32_16x16x32_bf16(pf1, vf, oacc[1][ns], 0, 0, 0);
        }
    }

#pragma unroll
    for (int t = 0; t < 2; ++t) {
#pragma unroll
        for (int g = 0; g < 4; ++g) {
            const float inv = 1.0f / lacc[t][g];
            const int qrow = q0 + t * 16 + quad * 4 + g;
            __hip_bfloat16* op = O + (size_t)(b * S_ + qrow) * ldo + h * D_;
#pragma unroll
            for (int ns = 0; ns < 8; ++ns)
                op[ns * 16 + r] = __float2bfloat16(oacc[t][ns][g] * inv);
        }
    }
}

// ---------------------------------------------------------------------------
extern "C" void kernel_launch(void* const* d_in, const int* in_sizes, int n_in,
                              void* d_out, int out_size, void* d_ws, size_t ws_size,
                              hipStream_t stream) {
    const void* x    = d_in[0];
    const void* cosp = d_in[1];
    const void* sinp = d_in[2];
    const void* Wq   = d_in[3];
    const void* Wk   = d_in[4];
    const void* Wv   = d_in[5];
    const void* Wo   = d_in[6];

    const int M = B_ * S_;                 // 4096
    const size_t MB = 1ull << 20;

    if (ws_size >= 28 * MB + 64) {
        // Fast path. ws: [0,16M)=xb then ao; [16M,28M)=Wqkv, then Wo at [16M,24M)
        // and packed-V at [24M,28M); flag at 28M.
        // d_out: qkv bf16 [4096,3072] (24 MB), then final output.
        char* ws = (char*)d_ws;
        bf16_t* xb = (bf16_t*)ws;
        bf16_t* wb = (bf16_t*)(ws + 16 * MB);
        bf16_t* wo = (bf16_t*)(ws + 16 * MB);
        unsigned* vp4 = (unsigned*)(ws + 24 * MB);
        bf16_t* ao = (bf16_t*)ws;
        int* flag  = (int*)(ws + 28 * MB);
        bf16_t* qkv = (bf16_t*)d_out;

        detect_dtype<<<1, 64, 0, stream>>>((const unsigned*)x, flag);

        // convert x, Wq, Wk, Wv -> bf16 (Wqkv contiguous [3072, 2048])
        Cseg sx{x,  xb,                          (B_ * S_ * HID_) / 8};
        Cseg sq{Wq, wb,                          (H_ * D_ * HID_) / 8};
        Cseg sk{Wk, wb + (size_t)2048 * HID_,    (HKV_ * D_ * HID_) / 8};
        Cseg sv{Wv, wb + (size_t)2560 * HID_,    (HKV_ * D_ * HID_) / 8};
        convert_bf16<<<dim3(4096, 4), 256, 0, stream>>>(sx, sq, sk, sv, flag);

        // Fused QKV projection: [4096,2048] x [3072,2048]^T -> qkv [4096,3072]
        gemm_lds<<<dim3(3072 / 128, M / 128), 256, 0, stream>>>(xb, wb, qkv, M, 3072, HID_, flag, 0);

        // convert Wo -> bf16 (wb dead; wo overlays wb)
        Cseg so{Wo, wo, (HID_ * H_ * D_) / 8};
        convert_bf16<<<dim3(2048, 1), 256, 0, stream>>>(so, so, so, so, flag);

        // pack V (no RoPE on V): qkv cols [2560,3072) -> vp4
        v_pack<<<(B_ * HKV_ * D_ * 64 * 16) / 256, 256, 0, stream>>>(
            (const __hip_bfloat16*)(qkv + 2560), vp4, 3072);

        // RoPE + RMSNorm in-place: q cols [0,2048), k cols [2048,2560)
        rope_rms<<<(B_ * S_ * H_) / 4, 256, 0, stream>>>((__hip_bfloat16*)qkv, cosp, sinp, H_, 3072, flag);
        rope_rms<<<(B_ * S_ * HKV_) / 4, 256, 0, stream>>>((__hip_bfloat16*)(qkv + 2048), cosp, sinp, HKV_, 3072, flag);

        // Flash attention v4: Q/K strided in qkv, V from vp4; O -> ao (xb dead)
        attn_flash4<<<dim3(256), 512, 0, stream>>>(
            (const __hip_bfloat16*)qkv, (const __hip_bfloat16*)(qkv + 2048),
            vp4, (__hip_bfloat16*)ao, 3072, 3072, 2048);

        // Output projection: ao x Wo^T -> d_out (fp32 if flag=0)
        gemm_lds<<<dim3(HID_ / 128, M / 128), 256, 0, stream>>>(ao, wo, d_out, M, HID_, H_ * D_, flag, 1);
    } else {
        // Fallback: proven path (ws >= 16 MB + 4).
        __hip_bfloat16* qb = (__hip_bfloat16*)d_ws;
        int* flag = (int*)((char*)d_ws + (size_t)M * (H_ * D_) * sizeof(__hip_bfloat16));
        __hip_bfloat16* kb = (__hip_bfloat16*)d_out;
        __hip_bfloat16* vb = kb + (size_t)M * (HKV_ * D_);

        detect_dtype<<<1, 64, 0, stream>>>((const unsigned*)x, flag);

        gemm_bt<<<dim3((H_ * D_) / 64, M / 64), 256, 0, stream>>>(x, Wq, qb, M, H_ * D_, HID_, flag, 0);
        gemm_bt<<<dim3((HKV_ * D_) / 64, M / 64), 256, 0, stream>>>(x, Wk, kb, M, HKV_ * D_, HID_, flag, 0);
        gemm_bt<<<dim3((HKV_ * D_) / 64, M / 64), 256, 0, stream>>>(x, Wv, vb, M, HKV_ * D_, HID_, flag, 0);

        rope_rms<<<(B_ * S_ * H_) / 4, 256, 0, stream>>>(qb, cosp, sinp, H_, H_ * D_, flag);
        rope_rms<<<(B_ * S_ * HKV_) / 4, 256, 0, stream>>>(kb, cosp, sinp, HKV_, HKV_ * D_, flag);

        attn_flash3<<<dim3(S_ / 32, B_ * HKV_), 256, 0, stream>>>(qb, kb, vb, qb, H_ * D_, HKV_ * D_, H_ * D_);

        gemm_bt<<<dim3(HID_ / 64, M / 64), 256, 0, stream>>>(qb, Wo, d_out, M, HID_, H_ * D_, flag, 1);
    }
}